// Round 9
// baseline (1221.721 us; speedup 1.0000x reference)
//
#include <hip/hip_runtime.h>

// RNN: S=512, B=128, I=256, H=512, O=128
// R13: 4-way column split. R12 (fence elision) confirmed: 1406->953us, fast
// path works. Decomposition of the remaining 4460 cyc/step: MFMA 1242, VALU
// ~1070, sync/latency ~2100. Fixed sync floor + scalable work -> quarter the
// scalable part: grid 32 = 8 groups x 4 col-quarters, 4 CUs/group.
//   - wave W owns 16 cols (c0 = q*128 + W*16): 1 nt x 16 kt = 16 W_hh frags
//     = 64 AGPRs (ALL weights register-resident), ~174 regs, 2 waves/SIMD.
//   - per CU/step: 128 MFMAs (621 cyc, was 1242), 4 tanh/thread (was 8).
//   - h exchange: own quarter (4 frags) via LDS dbuf; 12 partner frags via
//     plain b128 L2 reads (blocks {g,g+8,g+16,g+24} ≡ g mod 8 -> same XCD
//     round-robin; handshake verifies 3 partner XCC-IDs, slow path = fences).
//   - wave's 16 cols = half a frag -> single 8B store to global + LDS.
//   - 2-deep xh prefetch (xh[t+2] issued at step t): HBM latency never
//     exposed at the end-of-step vmcnt drain.
// R12 (kept): hang-proof handshake (RELEASE publish/ACQUIRE poll, bounded
// spin, observed-equality fast path), per-step fence elision on fast path.
// R10/R9/R8/R7/R5 (kept): LDS own-frag broadcast; t=0 read->barrier->store
// race fix; relaxed step-flag poll at step top; fast tanh; cvt_pk pack; xh
// folded into acc init.

typedef __attribute__((ext_vector_type(8))) short short8;   // 8 bf16
typedef __attribute__((ext_vector_type(4))) float f32x4;    // MFMA C/D
typedef __attribute__((ext_vector_type(2))) unsigned int uint2v;

__device__ __forceinline__ unsigned short f32_to_bf16(float f) {
  unsigned int u = __float_as_uint(f);
  u += 0x7FFFu + ((u >> 16) & 1u);
  return (unsigned short)(u >> 16);
}

// tanh(x) = 1 - 2/(e^{2x}+1) = 1 - 2*rcp(2^{2*log2e*x}+1).
__device__ __forceinline__ float tanh_fast(float x) {
  float e = __builtin_amdgcn_exp2f(x * 2.885390081777927f);  // 2*log2(e)
  float r = __builtin_amdgcn_rcpf(e + 1.0f);
  return __builtin_fmaf(-2.0f, r, 1.0f);
}

// D[15:0] = bf16(lo), D[31:16] = bf16(hi)
__device__ __forceinline__ unsigned cvt_pk_bf16(float lo, float hi) {
  unsigned r;
  asm("v_cvt_pk_bf16_f32 %0, %1, %2" : "=v"(r) : "v"(lo), "v"(hi));
  return r;
}

__device__ __forceinline__ float bf16_lo(unsigned u) {
  return __uint_as_float(u << 16);
}
__device__ __forceinline__ float bf16_hi(unsigned u) {
  return __uint_as_float(u & 0xFFFF0000u);
}

// ---------------------------------------------------------------------------
// Pack K x N fp32 row-major -> bf16 MFMA fragment tiles.
// Tile (nt,kt): lane holds W[k=kt*32+(lane>>4)*8+j][n=nt*16+(lane&15)],
// stored P[tile*512 + lane*8 + j], tile = nt*(K/32)+kt.
// ---------------------------------------------------------------------------
__global__ void pack_b_kernel(const float* __restrict__ W,
                              unsigned short* __restrict__ P, int K, int N) {
  int tid  = blockIdx.x * 256 + threadIdx.x;
  int lane = tid & 63;
  int tile = tid >> 6;
  int nKt  = K >> 5;
  int nTiles = (N >> 4) * nKt;
  if (tile >= nTiles) return;
  int nt = tile / nKt;
  int kt = tile - nt * nKt;
  int n  = (nt << 4) + (lane & 15);
  int k0 = (kt << 5) + ((lane >> 4) << 3);
  unsigned short* dst = P + (size_t)tile * 512 + lane * 8;
#pragma unroll
  for (int j = 0; j < 8; ++j)
    dst[j] = f32_to_bf16(W[(size_t)(k0 + j) * N + n]);
}

// flags[(g*4+q)*32 + 0] = step flag; [+1] = XCC id (sentinel -1).
__global__ void init_flags_kernel(int* __restrict__ flags) {
  if (threadIdx.x < 32) {
    flags[threadIdx.x * 32] = 0;
    flags[threadIdx.x * 32 + 1] = -1;
  }
}

// ---------------------------------------------------------------------------
// Phase 1: xh = x@W_xh + b_h, swapped-operand MFMA; stored pre-swizzled:
// xh_s[((t*8+g)*4 + by)*2048 + lane*32 + nt*4 + r] =
//   xh[t][g*16 + (lane&15)][by*128 + nt*16 + (lane>>4)*4 + r]
// grid 1024; by-loop internal so x is read from HBM exactly once.
// ---------------------------------------------------------------------------
__global__ __launch_bounds__(256) void xh_gemm_kernel(
    const float* __restrict__ x, const unsigned short* __restrict__ Wxh_p,
    const float* __restrict__ b_h, unsigned short* __restrict__ xh_s) {
  __shared__ __align__(16) unsigned short Abuf[64 * 264];
  const int tid = threadIdx.x;
  const int m0 = blockIdx.x * 64;

#pragma unroll
  for (int i = 0; i < 16; ++i) {
    int flat = i * 1024 + tid * 4;
    int row = flat >> 8, col = flat & 255;
    float4 v = *(const float4*)(x + (size_t)(m0 + row) * 256 + col);
    ushort4 u;
    u.x = f32_to_bf16(v.x); u.y = f32_to_bf16(v.y);
    u.z = f32_to_bf16(v.z); u.w = f32_to_bf16(v.w);
    *(ushort4*)(Abuf + row * 264 + col) = u;
  }
  __syncthreads();

  const int w2 = tid >> 6, lane = tid & 63;
  const int quad = lane >> 4, col16 = lane & 15;
  const int aBase = (w2 * 16 + col16) * 264 + quad * 8;
  const int t = (m0 + w2 * 16) >> 7;
  const int g = ((m0 + w2 * 16) & 127) >> 4;

  for (int by = 0; by < 4; ++by) {
    f32x4 acc[8];
#pragma unroll
    for (int nt = 0; nt < 8; ++nt) acc[nt] = (f32x4){0.f,0.f,0.f,0.f};
#pragma unroll
    for (int kt = 0; kt < 8; ++kt) {
      short8 xfrag = *(const short8*)(Abuf + aBase + kt * 32);
#pragma unroll
      for (int nt = 0; nt < 8; ++nt) {
        int tile = (by * 8 + nt) * 8 + kt;      // nKt(Wxh)=8
        short8 wfrag = *(const short8*)(Wxh_p + (size_t)tile * 512 + lane * 8);
        acc[nt] = __builtin_amdgcn_mfma_f32_16x16x32_bf16(wfrag, xfrag, acc[nt], 0, 0, 0);
      }
    }
    unsigned short hv[32];
#pragma unroll
    for (int nt = 0; nt < 8; ++nt) {
      float4 bh4 = *(const float4*)(b_h + by * 128 + nt * 16 + quad * 4);
#pragma unroll
      for (int r = 0; r < 4; ++r)
        hv[nt * 4 + r] = f32_to_bf16(acc[nt][r] + (&bh4.x)[r]);
    }
    unsigned short* dst = xh_s + ((size_t)(t * 8 + g) * 4 + by) * 2048 + lane * 32;
#pragma unroll
    for (int k = 0; k < 4; ++k) {
      uint4 u;
      u.x = (unsigned)hv[k*8+0] | ((unsigned)hv[k*8+1] << 16);
      u.y = (unsigned)hv[k*8+2] | ((unsigned)hv[k*8+3] << 16);
      u.z = (unsigned)hv[k*8+4] | ((unsigned)hv[k*8+5] << 16);
      u.w = (unsigned)hv[k*8+6] | ((unsigned)hv[k*8+7] << 16);
      *(uint4*)(dst + k * 8) = u;
    }
  }
}

// ---------------------------------------------------------------------------
// Phase 2: recurrence. grid 32 (g = blockIdx&7, q = blockIdx>>3), block 512
// = 8 waves (2/SIMD). Window (t,g) = xhs + (t*8+g)*8192 shorts:
//   xh input : quarter q's cols = by q, shorts [q*2048, q*2048+2048)
//   h output : frag F (== kt) at F*512 + lane*8; quarter owns F in
//              [q*4, q*4+4) == the same shorts as its xh block (in-place).
// Wave W owns cols c0 = q*128 + W*16 -> half of frag F = q*4 + (W>>1).
// LDS: Hlds[t&1] holds own-quarter h_{t-1} frags (local idx 0..3) for step t.
// ---------------------------------------------------------------------------
__global__ __launch_bounds__(512, 2) void rnn_recurrence_kernel(
    const unsigned short* __restrict__ Whh_p,
    unsigned short* __restrict__ xhs,            // xh in, hs out (in-place)
    int* __restrict__ flags) {
  __shared__ __align__(16) unsigned short Hlds[2][4 * 512];   // 8 KB
  __shared__ int fastSh;
  const int tid = threadIdx.x;
  const int W = tid >> 6, lane = tid & 63;
  const int quad = lane >> 4, col16 = lane & 15;
  const int g = blockIdx.x & 7, q = blockIdx.x >> 3;

  // ---- XCD handshake (hang-proof): RELEASE publish + ACQUIRE poll, bounded
  // spin; fast only if ALL 3 partners observed on my XCD. Timeout -> slow.
  int myx;
  asm volatile("s_getreg_b32 %0, hwreg(HW_REG_XCC_ID)" : "=s"(myx));
  if (tid == 0) {
    __hip_atomic_store(&flags[(g * 4 + q) * 32 + 1], myx,
                       __ATOMIC_RELEASE, __HIP_MEMORY_SCOPE_AGENT);
    int ok = 1;
    for (int j = 1; j < 4; ++j) {
      int qq = (q + j) & 3;
      int pv = -1;
      for (int spin = 0; spin < (1 << 20) && pv == -1; ++spin)
        pv = __hip_atomic_load(&flags[(g * 4 + qq) * 32 + 1],
                               __ATOMIC_ACQUIRE, __HIP_MEMORY_SCOPE_AGENT);
      ok &= (pv == myx);
    }
    fastSh = ok;
  }

  // 16 weight frags -> 64 AGPRs (entire per-wave weight set resident).
  // wf[kk]: nt = q*8+W, kt = (q*4+kk)&15 -> kk 0..3 own-quarter kts,
  // kk 4..15 partner kts in cyclic order. Indices compile-time (rule #20).
  short8 wf[16];
#pragma unroll
  for (int kk = 0; kk < 16; ++kk) {
    int kt = (q * 4 + kk) & 15;
    wf[kk] = *(const short8*)(
        Whh_p + ((size_t)((q * 8 + W) * 16 + kt)) * 512 + lane * 8);
  }
#pragma unroll
  for (int f = 0; f < 16; ++f) asm volatile("" : "+a"(wf[f]));

  int* flagSelf = flags + (g * 4 + q) * 32;
  int* flagP1 = flags + (g * 4 + ((q + 1) & 3)) * 32;
  int* flagP2 = flags + (g * 4 + ((q + 2) & 3)) * 32;
  int* flagP3 = flags + (g * 4 + ((q + 3) & 3)) * 32;

  // xh read: cols c0 + quad*4 + r -> by = q, in-by nt = W, shorts
  // [W*4, W*4+4) of the lane*32 run: one 8B uint2.
  const unsigned short* xhL =
      xhs + (size_t)g * 8192 + q * 2048 + lane * 32 + W * 4;

  // Epilogue store: frag F = q*4+(W>>1), within-frag col = (W&1)*16+quad*4+r
  // -> lane' = ((W&1)*2 + (quad>>1))*16 + col16, j0 = (quad&1)*4.
  const int F = q * 4 + (W >> 1);
  const int eIn = ((W & 1) * 2 + (quad >> 1)) * 128 + col16 * 8 + (quad & 1) * 4;
  const int eBase = F * 512 + eIn;               // global (window-relative)
  const int lOff = (W >> 1) * 512 + eIn;         // LDS own-frag offset

  // ---- t = 0: h_0 = tanh(xh[0]); also prime the 2-deep xh prefetch ----
  uint2 xq0 = *(const uint2*)(xhL);
  uint2 xqA = *(const uint2*)(xhL + 65536);          // xh[1]
  uint2 xqB = *(const uint2*)(xhL + 2 * 65536);      // xh[2]
  __syncthreads();   // R9 race fix: all xh[0] reads complete before h_0 store
  const bool fast = (fastSh != 0);
  {
    unsigned short* winCur = xhs + (size_t)g * 8192;
    float h0 = tanh_fast(bf16_lo(xq0.x));
    float h1 = tanh_fast(bf16_hi(xq0.x));
    float h2 = tanh_fast(bf16_lo(xq0.y));
    float h3 = tanh_fast(bf16_hi(xq0.y));
    uint2v o;
    o.x = cvt_pk_bf16(h0, h1);
    o.y = cvt_pk_bf16(h2, h3);
    *(uint2v*)(winCur + eBase) = o;                 // global hs
    *(uint2v*)(&Hlds[1][lOff]) = o;                 // LDS buf[1]
    __syncthreads();   // vmcnt+lgkm drain: h_0 in L2 and LDS
    if (tid == 0) {
      if (!fast) __builtin_amdgcn_fence(__ATOMIC_RELEASE, "agent");
      __hip_atomic_store(flagSelf, 1, __ATOMIC_RELAXED, __HIP_MEMORY_SCOPE_AGENT);
    }
  }

#pragma unroll 1
  for (int t = 1; t < 512; ++t) {
    const unsigned short* winPrev = xhs + ((size_t)(t - 1) * 8 + g) * 8192;
    unsigned short* winCur = xhs + ((size_t)t * 8 + g) * 8192;
    const unsigned short* bufR = Hlds[t & 1];
    unsigned short* bufW = Hlds[(t & 1) ^ 1];

    // Own-quarter h frags from LDS (all 8 waves wrote last step; ordered by
    // the end-of-step barrier).
    short8 hf0 = *(const short8*)(bufR + 0 * 512 + lane * 8);
    short8 hf1 = *(const short8*)(bufR + 1 * 512 + lane * 8);
    short8 hf2 = *(const short8*)(bufR + 2 * 512 + lane * 8);
    short8 hf3 = *(const short8*)(bufR + 3 * 512 + lane * 8);

    // Poll 3 partner flags (relaxed; in lockstep already set; first poll
    // dominates, the rest are usually immediate).
    while (__hip_atomic_load(flagP1, __ATOMIC_RELAXED, __HIP_MEMORY_SCOPE_AGENT) < t) {}
    while (__hip_atomic_load(flagP2, __ATOMIC_RELAXED, __HIP_MEMORY_SCOPE_AGENT) < t) {}
    while (__hip_atomic_load(flagP3, __ATOMIC_RELAXED, __HIP_MEMORY_SCOPE_AGENT) < t) {}
    if (!fast) __builtin_amdgcn_fence(__ATOMIC_ACQUIRE, "agent");
    asm volatile("" ::: "memory");   // no compiler hoist of loads above poll

    // Partner h frags (12): plain b128 from the shared same-XCD L2 (L1-cold
    // by construction). Latency covered by acc init + own MFMAs.
    short8 pf[12];
#pragma unroll
    for (int i = 0; i < 12; ++i) {
      int kt = (q * 4 + 4 + i) & 15;              // frag index == kt
      pf[i] = *(const short8*)(winPrev + (size_t)kt * 512 + lane * 8);
    }

    // acc init = xh[t]; rotate the 2-deep prefetch (xqB arrived: issued a
    // full step ago), then issue xh[t+2].
    f32x4 acc;
    acc[0] = bf16_lo(xqA.x); acc[1] = bf16_hi(xqA.x);
    acc[2] = bf16_lo(xqA.y); acc[3] = bf16_hi(xqA.y);
    xqA = xqB;
    if (t < 510) xqB = *(const uint2*)(xhL + (size_t)(t + 2) * 65536);

    // Own-quarter MFMAs (kk 0..3) -- cover partner-load latency.
    acc = __builtin_amdgcn_mfma_f32_16x16x32_bf16(wf[0], hf0, acc, 0, 0, 0);
    acc = __builtin_amdgcn_mfma_f32_16x16x32_bf16(wf[1], hf1, acc, 0, 0, 0);
    acc = __builtin_amdgcn_mfma_f32_16x16x32_bf16(wf[2], hf2, acc, 0, 0, 0);
    acc = __builtin_amdgcn_mfma_f32_16x16x32_bf16(wf[3], hf3, acc, 0, 0, 0);

    // Partner MFMAs (kk 4..15).
#pragma unroll
    for (int kk = 4; kk < 16; ++kk)
      acc = __builtin_amdgcn_mfma_f32_16x16x32_bf16(wf[kk], pf[kk - 4], acc, 0, 0, 0);

    // Epilogue: h_t = tanh(acc); one 8B store each to global + LDS.
    {
      float t0 = tanh_fast(acc[0]);
      float t1 = tanh_fast(acc[1]);
      float t2 = tanh_fast(acc[2]);
      float t3 = tanh_fast(acc[3]);
      uint2v o;
      o.x = cvt_pk_bf16(t0, t1);
      o.y = cvt_pk_bf16(t2, t3);
      *(uint2v*)(winCur + eBase) = o;
      *(uint2v*)(&bufW[lOff]) = o;
    }

    // Single barrier: drains vmcnt (h stores ack'd in L2, xh prefetch) +
    // lgkm (LDS) for all waves; then tid0 publishes. Fast: relaxed store
    // (same-XCD L2 order). Slow: release fence (wbL2) first.
    __syncthreads();
    if (tid == 0) {
      if (!fast) __builtin_amdgcn_fence(__ATOMIC_RELEASE, "agent");
      __hip_atomic_store(flagSelf, t + 1, __ATOMIC_RELAXED, __HIP_MEMORY_SCOPE_AGENT);
    }
  }
}

// ---------------------------------------------------------------------------
// Phase 3: out = hs @ W_hy + b_y.  hs is in frag layout:
// window (m0>>4) at (m0>>4)*8192 shorts, frag kt at kt*512 + lane*8.
// ---------------------------------------------------------------------------
__global__ __launch_bounds__(256) void out_gemm_kernel(
    const unsigned short* __restrict__ hs, const unsigned short* __restrict__ Why_p,
    const float* __restrict__ b_y, float* __restrict__ out) {
  const int tid = threadIdx.x;
  const int w = tid >> 6, lane = tid & 63;
  const int quad = lane >> 4, col16 = lane & 15;
  const int m0 = blockIdx.x * 64 + w * 16;

  f32x4 acc[8];
#pragma unroll
  for (int nt = 0; nt < 8; ++nt) acc[nt] = (f32x4){0.f,0.f,0.f,0.f};

  const unsigned short* aP = hs + (size_t)(m0 >> 4) * 8192 + lane * 8;
#pragma unroll
  for (int kt = 0; kt < 16; ++kt) {
    short8 a = *(const short8*)(aP + kt * 512);
#pragma unroll
    for (int nt = 0; nt < 8; ++nt) {
      int tile = nt * 16 + kt;                 // nKt(Why)=16
      short8 b = *(const short8*)(Why_p + (size_t)tile * 512 + lane * 8);
      acc[nt] = __builtin_amdgcn_mfma_f32_16x16x32_bf16(a, b, acc[nt], 0, 0, 0);
    }
  }
#pragma unroll
  for (int nt = 0; nt < 8; ++nt) {
    int n = nt * 16 + col16;
    float by = b_y[n];
#pragma unroll
    for (int r = 0; r < 4; ++r)
      out[(size_t)(m0 + quad * 4 + r) * 128 + n] = acc[nt][r] + by;
  }
}

// ---------------------------------------------------------------------------
extern "C" void kernel_launch(void* const* d_in, const int* in_sizes, int n_in,
                              void* d_out, int out_size, void* d_ws, size_t ws_size,
                              hipStream_t stream) {
  const float* x    = (const float*)d_in[0];   // [512,128,256]
  const float* W_xh = (const float*)d_in[1];   // [256,512]
  const float* W_hh = (const float*)d_in[2];   // [512,512]
  const float* W_hy = (const float*)d_in[3];   // [512,128]
  const float* b_h  = (const float*)d_in[4];   // [512]
  const float* b_y  = (const float*)d_in[5];   // [128]
  float* out = (float*)d_out;                  // [512,128,128]

  char* ws = (char*)d_ws;
  unsigned short* Wxh_p = (unsigned short*)(ws);                 // 256 KB
  unsigned short* Whh_p = (unsigned short*)(ws + (256 << 10));   // 512 KB
  unsigned short* Why_p = (unsigned short*)(ws + (768 << 10));   // 128 KB
  int*            flags = (int*)(ws + (960 << 10));              // 4 KB
  unsigned short* xhs   = (unsigned short*)(ws + (1024 << 10));  // 64 MB

  pack_b_kernel<<<64, 256, 0, stream>>>(W_xh, Wxh_p, 256, 512);
  pack_b_kernel<<<128, 256, 0, stream>>>(W_hh, Whh_p, 512, 512);
  pack_b_kernel<<<32, 256, 0, stream>>>(W_hy, Why_p, 512, 128);
  init_flags_kernel<<<1, 64, 0, stream>>>(flags);

  xh_gemm_kernel<<<1024, 256, 0, stream>>>(x, Wxh_p, b_h, xhs);

  rnn_recurrence_kernel<<<32, 512, 0, stream>>>(Whh_p, xhs, flags);

  out_gemm_kernel<<<1024, 256, 0, stream>>>(xhs, Why_p, b_y, out);
}

// Round 11
// 975.367 us; speedup vs baseline: 1.2526x; 1.2526x over previous
//
#include <hip/hip_runtime.h>

// RNN: S=512, B=128, I=256, H=512, O=128
// R15 = R14 + bounded polls (hang-proofing). R14's bench died with a
// container failure; dependence-graph audit found no deadlock (phase
// protocol acyclic by induction; all window hazards barrier-ordered), so
// either infra flake or a flag-propagation liveness issue. Defense: EVERY
// spin loop now bounded (2^16 iters, ~1000x normal margin measured in R12);
// a stall now yields a fast wrong-answer pytest report instead of a
// watchdog kill. No schedule changes vs R14.
// R14: software-pipelined step (R13's 4-CU split regressed -> sync-floor
// dominated; back to 2-CU grid 16). Own-half MFMAs for t+1 need only MY
// h_t, so: A partner MFMAs (pf preloaded) | B tanh + h_t stores | C
// materialize xh[t+1] pre-barrier | D barrier + flag t+1 | E ds_read own
// h_t, accN=xh[t+1], poll partner>=t+1 (~immediate), issue pf loads, own
// MFMAs cover load latency. Poll-wait ~0; pf latency hidden; barrier never
// drains an in-flight xh load; prefetch-consume pre-barrier vs overwrite
// post-barrier excludes the R8-class race structurally.
// R12 (kept): hang-proof XCD handshake (RELEASE publish/ACQUIRE poll,
// bounded spin, observed-equality fast path); per-step agent-fence elision
// on fast path; slow path keeps fences (correct on any mapping).
// R10/R9/R8/R7/R5 (kept): LDS own-frag broadcast; t=0 read->barrier->store
// race fix; 8 waves 2/SIMD, 32 W_hh frags = 128 AGPRs/wave; relaxed
// step-flag poll; fast tanh; cvt_pk pack; xh folded into acc init.

typedef __attribute__((ext_vector_type(8))) short short8;   // 8 bf16
typedef __attribute__((ext_vector_type(4))) float f32x4;    // MFMA C/D
typedef __attribute__((ext_vector_type(2))) unsigned int uint2v;

#define POLL_BOUND (1 << 16)

__device__ __forceinline__ unsigned short f32_to_bf16(float f) {
  unsigned int u = __float_as_uint(f);
  u += 0x7FFFu + ((u >> 16) & 1u);
  return (unsigned short)(u >> 16);
}

// tanh(x) = 1 - 2/(e^{2x}+1) = 1 - 2*rcp(2^{2*log2e*x}+1).
__device__ __forceinline__ float tanh_fast(float x) {
  float e = __builtin_amdgcn_exp2f(x * 2.885390081777927f);  // 2*log2(e)
  float r = __builtin_amdgcn_rcpf(e + 1.0f);
  return __builtin_fmaf(-2.0f, r, 1.0f);
}

// D[15:0] = bf16(lo), D[31:16] = bf16(hi)
__device__ __forceinline__ unsigned cvt_pk_bf16(float lo, float hi) {
  unsigned r;
  asm("v_cvt_pk_bf16_f32 %0, %1, %2" : "=v"(r) : "v"(lo), "v"(hi));
  return r;
}

__device__ __forceinline__ float bf16_lo(unsigned u) {
  return __uint_as_float(u << 16);
}
__device__ __forceinline__ float bf16_hi(unsigned u) {
  return __uint_as_float(u & 0xFFFF0000u);
}

// Bounded poll: returns when *p >= v or after POLL_BOUND tries.
__device__ __forceinline__ void poll_ge(int* p, int v) {
  for (int spin = 0; spin < POLL_BOUND; ++spin) {
    if (__hip_atomic_load(p, __ATOMIC_RELAXED, __HIP_MEMORY_SCOPE_AGENT) >= v)
      return;
  }
}

// ---------------------------------------------------------------------------
// Pack K x N fp32 row-major -> bf16 MFMA fragment tiles.
// Tile (nt,kt): lane holds W[k=kt*32+(lane>>4)*8+j][n=nt*16+(lane&15)],
// stored P[tile*512 + lane*8 + j], tile = nt*(K/32)+kt.
// ---------------------------------------------------------------------------
__global__ void pack_b_kernel(const float* __restrict__ W,
                              unsigned short* __restrict__ P, int K, int N) {
  int tid  = blockIdx.x * 256 + threadIdx.x;
  int lane = tid & 63;
  int tile = tid >> 6;
  int nKt  = K >> 5;
  int nTiles = (N >> 4) * nKt;
  if (tile >= nTiles) return;
  int nt = tile / nKt;
  int kt = tile - nt * nKt;
  int n  = (nt << 4) + (lane & 15);
  int k0 = (kt << 5) + ((lane >> 4) << 3);
  unsigned short* dst = P + (size_t)tile * 512 + lane * 8;
#pragma unroll
  for (int j = 0; j < 8; ++j)
    dst[j] = f32_to_bf16(W[(size_t)(k0 + j) * N + n]);
}

// flags[(g*2+half)*32 + 0] = step flag; [+1] = XCC id (sentinel -1).
__global__ void init_flags_kernel(int* __restrict__ flags) {
  if (threadIdx.x < 16) {
    flags[threadIdx.x * 32] = 0;
    flags[threadIdx.x * 32 + 1] = -1;
  }
}

// ---------------------------------------------------------------------------
// Phase 1: xh = x@W_xh + b_h, swapped-operand MFMA; stored pre-swizzled:
// xh_s[((t*8+g)*4 + by)*2048 + lane*32 + nt*4 + r] =
//   xh[t][g*16 + (lane&15)][by*128 + nt*16 + (lane>>4)*4 + r]
// grid 1024; by-loop internal so x is read from HBM exactly once.
// ---------------------------------------------------------------------------
__global__ __launch_bounds__(256) void xh_gemm_kernel(
    const float* __restrict__ x, const unsigned short* __restrict__ Wxh_p,
    const float* __restrict__ b_h, unsigned short* __restrict__ xh_s) {
  __shared__ __align__(16) unsigned short Abuf[64 * 264];
  const int tid = threadIdx.x;
  const int m0 = blockIdx.x * 64;

#pragma unroll
  for (int i = 0; i < 16; ++i) {
    int flat = i * 1024 + tid * 4;
    int row = flat >> 8, col = flat & 255;
    float4 v = *(const float4*)(x + (size_t)(m0 + row) * 256 + col);
    ushort4 u;
    u.x = f32_to_bf16(v.x); u.y = f32_to_bf16(v.y);
    u.z = f32_to_bf16(v.z); u.w = f32_to_bf16(v.w);
    *(ushort4*)(Abuf + row * 264 + col) = u;
  }
  __syncthreads();

  const int w2 = tid >> 6, lane = tid & 63;
  const int quad = lane >> 4, col16 = lane & 15;
  const int aBase = (w2 * 16 + col16) * 264 + quad * 8;
  const int t = (m0 + w2 * 16) >> 7;
  const int g = ((m0 + w2 * 16) & 127) >> 4;

  for (int by = 0; by < 4; ++by) {
    f32x4 acc[8];
#pragma unroll
    for (int nt = 0; nt < 8; ++nt) acc[nt] = (f32x4){0.f,0.f,0.f,0.f};
#pragma unroll
    for (int kt = 0; kt < 8; ++kt) {
      short8 xfrag = *(const short8*)(Abuf + aBase + kt * 32);
#pragma unroll
      for (int nt = 0; nt < 8; ++nt) {
        int tile = (by * 8 + nt) * 8 + kt;      // nKt(Wxh)=8
        short8 wfrag = *(const short8*)(Wxh_p + (size_t)tile * 512 + lane * 8);
        acc[nt] = __builtin_amdgcn_mfma_f32_16x16x32_bf16(wfrag, xfrag, acc[nt], 0, 0, 0);
      }
    }
    unsigned short hv[32];
#pragma unroll
    for (int nt = 0; nt < 8; ++nt) {
      float4 bh4 = *(const float4*)(b_h + by * 128 + nt * 16 + quad * 4);
#pragma unroll
      for (int r = 0; r < 4; ++r)
        hv[nt * 4 + r] = f32_to_bf16(acc[nt][r] + (&bh4.x)[r]);
    }
    unsigned short* dst = xh_s + ((size_t)(t * 8 + g) * 4 + by) * 2048 + lane * 32;
#pragma unroll
    for (int k = 0; k < 4; ++k) {
      uint4 u;
      u.x = (unsigned)hv[k*8+0] | ((unsigned)hv[k*8+1] << 16);
      u.y = (unsigned)hv[k*8+2] | ((unsigned)hv[k*8+3] << 16);
      u.z = (unsigned)hv[k*8+4] | ((unsigned)hv[k*8+5] << 16);
      u.w = (unsigned)hv[k*8+6] | ((unsigned)hv[k*8+7] << 16);
      *(uint4*)(dst + k * 8) = u;
    }
  }
}

// ---------------------------------------------------------------------------
// Phase 2: recurrence. grid 16 (g = blockIdx&7, half = blockIdx>>3),
// block 512 = 8 waves (2/SIMD). Window (t,g) = xhs + (t*8+g)*8192 shorts:
//   xh input : half's shorts [half*4096, half*4096+4096)
//   h output : frag F in [half*8, half*8+8) at F*512 + lane*8 (shorts)
// Wave W owns cols c0 = half*256 + W*32 -> writes exactly frag half*8+W.
// LDS: Hlds[t&1] holds own-half h_t frags (LOCAL index 0..7 = wave W).
// ---------------------------------------------------------------------------
__global__ __launch_bounds__(512, 2) void rnn_recurrence_kernel(
    const unsigned short* __restrict__ Whh_p,
    unsigned short* __restrict__ xhs,            // xh in, hs out (in-place)
    int* __restrict__ flags) {
  __shared__ __align__(16) unsigned short Hlds[2][8 * 512];   // 16 KB
  __shared__ int fastSh;
  const int tid = threadIdx.x;
  const int W = tid >> 6, lane = tid & 63;
  const int quad = lane >> 4, col16 = lane & 15;
  const int g = blockIdx.x & 7, half = blockIdx.x >> 3;

  // ---- XCD handshake (hang-proof): RELEASE publish + ACQUIRE poll with a
  // bounded spin. fast=true only on OBSERVED id equality; timeout -> slow.
  int myx;
  asm volatile("s_getreg_b32 %0, hwreg(HW_REG_XCC_ID)" : "=s"(myx));
  if (tid == 0) {
    __hip_atomic_store(&flags[(g * 2 + half) * 32 + 1], myx,
                       __ATOMIC_RELEASE, __HIP_MEMORY_SCOPE_AGENT);
    int pv = -1;
    for (int spin = 0; spin < (1 << 20) && pv == -1; ++spin)
      pv = __hip_atomic_load(&flags[(g * 2 + (half ^ 1)) * 32 + 1],
                             __ATOMIC_ACQUIRE, __HIP_MEMORY_SCOPE_AGENT);
    fastSh = (pv == myx);
  }

  // 32 weight frags -> 128 AGPRs. wf[p*16+kk]: NT = half*16 + W*2 + p,
  // kt = (half*8+kk)&15: kk 0..7 own-half kts, kk 8..15 partner-half kts.
  short8 wf[32];
#pragma unroll
  for (int p = 0; p < 2; ++p)
#pragma unroll
    for (int kk = 0; kk < 16; ++kk) {
      int kt = (half * 8 + kk) & 15;
      wf[p * 16 + kk] = *(const short8*)(
          Whh_p + ((size_t)((half * 16 + W * 2 + p) * 16 + kt)) * 512 + lane * 8);
    }
#pragma unroll
  for (int f = 0; f < 32; ++f) asm volatile("" : "+a"(wf[f]));

  int* flagSelf = flags + (g * 2 + half) * 32;
  int* flagPart = flags + (g * 2 + (half ^ 1)) * 32;

  // xh read: cols c0 + p*16 + quad*4 + r, c0 = half*256 + W*32 ->
  // by = half*2 + (W>>2); in-by nt = (W&3)*2 + p; one uint4 covers both p.
  const unsigned short* xhL =
      xhs + (size_t)g * 8192 + (half * 2 + (W >> 2)) * 2048 + lane * 32 + (W & 3) * 8;

  // Epilogue store: frag F = half*8 + W; element (p,quad,col16) ->
  // offset = eBase + p*256, eBase = F*512 + (quad>>1)*128 + col16*8 + (quad&1)*4.
  const int fragOwn = half * 8 + W;
  const int eIn = (quad >> 1) * 128 + col16 * 8 + (quad & 1) * 4;
  const int eBase = fragOwn * 512 + eIn;         // global (window-relative)
  const int lOff = W * 512 + eIn;                // LDS local frag offset

  // ---- t = 0 prologue: h_0 = tanh(xh[0]) (h_{-1} = 0) ----
  // R9 race fix: xh[0]/xh[1] loads complete at barrier#1, before h_0 store.
  uint4 xq0 = *(const uint4*)(xhL);
  uint4 xqUse = *(const uint4*)(xhL + 65536);        // xh[1] value
  __syncthreads();                                   // barrier#1
  const bool fast = (fastSh != 0);
  {
    unsigned short* win0 = xhs + (size_t)g * 8192;
    unsigned xw[4] = {xq0.x, xq0.y, xq0.z, xq0.w};
#pragma unroll
    for (int p = 0; p < 2; ++p) {
      float v0 = tanh_fast(bf16_lo(xw[p * 2 + 0]));
      float v1 = tanh_fast(bf16_hi(xw[p * 2 + 0]));
      float v2 = tanh_fast(bf16_lo(xw[p * 2 + 1]));
      float v3 = tanh_fast(bf16_hi(xw[p * 2 + 1]));
      uint2v o;
      o.x = cvt_pk_bf16(v0, v1);
      o.y = cvt_pk_bf16(v2, v3);
      *(uint2v*)(win0 + eBase + p * 256) = o;          // global hs
      *(uint2v*)(&Hlds[0][lOff + p * 256]) = o;        // LDS buf[0]
    }
    __syncthreads();                                   // barrier#2: h_0 drained
    if (tid == 0) {
      if (!fast) __builtin_amdgcn_fence(__ATOMIC_RELEASE, "agent");
      __hip_atomic_store(flagSelf, 1, __ATOMIC_RELAXED, __HIP_MEMORY_SCOPE_AGENT);
    }
  }

  // ---- prologue tail (E for t=0): prepare iter 1 ----
  uint4 xqIn = *(const uint4*)(xhL + 2 * 65536);       // issue xh[2]
  short8 hf[8];
#pragma unroll
  for (int kk = 0; kk < 8; ++kk)                       // own h_0 from LDS
    hf[kk] = *(const short8*)(&Hlds[0][kk * 512 + lane * 8]);
  f32x4 acc[2];
#pragma unroll
  for (int p = 0; p < 2; ++p) {                        // acc = xh[1]
    unsigned u0 = (p == 0) ? xqUse.x : xqUse.z;
    unsigned u1 = (p == 0) ? xqUse.y : xqUse.w;
    acc[p][0] = bf16_lo(u0); acc[p][1] = bf16_hi(u0);
    acc[p][2] = bf16_lo(u1); acc[p][3] = bf16_hi(u1);
  }
  poll_ge(flagPart, 1);
  if (!fast) __builtin_amdgcn_fence(__ATOMIC_ACQUIRE, "agent");
  asm volatile("" ::: "memory");
  short8 pf[8];
#pragma unroll
  for (int kk = 0; kk < 8; ++kk)                       // partner h_0 (win 0)
    pf[kk] = *(const short8*)(xhs + (size_t)g * 8192 +
                              ((size_t)((half ^ 1) * 8 + kk)) * 512 + lane * 8);
#pragma unroll
  for (int kk = 0; kk < 8; ++kk)                       // own MFMAs for t=1
#pragma unroll
    for (int p = 0; p < 2; ++p)
      acc[p] = __builtin_amdgcn_mfma_f32_16x16x32_bf16(wf[p * 16 + kk], hf[kk], acc[p], 0, 0, 0);

#pragma unroll 1
  for (int t = 1; t < 512; ++t) {
    unsigned short* winCur = xhs + ((size_t)t * 8 + g) * 8192;

    // A: partner MFMAs (pf = partner h_{t-1}, preloaded in previous tail).
#pragma unroll
    for (int kk = 0; kk < 8; ++kk)
#pragma unroll
      for (int p = 0; p < 2; ++p)
        acc[p] = __builtin_amdgcn_mfma_f32_16x16x32_bf16(wf[p * 16 + 8 + kk], pf[kk], acc[p], 0, 0, 0);

    // B: h_t = tanh(acc); store global (partner + phase 3) + LDS own frag.
    unsigned short* bufW = &Hlds[t & 1][0];
#pragma unroll
    for (int p = 0; p < 2; ++p) {
      float t0 = tanh_fast(acc[p][0]);
      float t1 = tanh_fast(acc[p][1]);
      float t2 = tanh_fast(acc[p][2]);
      float t3 = tanh_fast(acc[p][3]);
      uint2v o;
      o.x = cvt_pk_bf16(t0, t1);
      o.y = cvt_pk_bf16(t2, t3);
      *(uint2v*)(winCur + eBase + p * 256) = o;
      *(uint2v*)(&bufW[lOff + p * 256]) = o;
    }

    // C: materialize xh[t+1] (issued in previous tail) BEFORE the barrier,
    // so D's vmcnt drain only waits on the h stores just issued.
    xqUse = xqIn;

    // D: barrier (h stores + LDS writes drained for all waves); publish.
    __syncthreads();
    if (tid == 0) {
      if (!fast) __builtin_amdgcn_fence(__ATOMIC_RELEASE, "agent");
      __hip_atomic_store(flagSelf, t + 1, __ATOMIC_RELAXED, __HIP_MEMORY_SCOPE_AGENT);
    }

    // E: prepare step t+1 (skipped at t=511).
    if (t < 511) {
      // issue xh[t+2] (consumed at next C; window overwritten at t+2 -> safe)
      if (t < 510) xqIn = *(const uint4*)(xhL + (size_t)(t + 2) * 65536);
      // own h_t frags from LDS (ordered by D's barrier)
#pragma unroll
      for (int kk = 0; kk < 8; ++kk)
        hf[kk] = *(const short8*)(&bufW[kk * 512 + lane * 8]);
      // accN = xh[t+1]
      f32x4 accN[2];
#pragma unroll
      for (int p = 0; p < 2; ++p) {
        unsigned u0 = (p == 0) ? xqUse.x : xqUse.z;
        unsigned u1 = (p == 0) ? xqUse.y : xqUse.w;
        accN[p][0] = bf16_lo(u0); accN[p][1] = bf16_hi(u0);
        accN[p][2] = bf16_lo(u1); accN[p][3] = bf16_hi(u1);
      }
      // poll partner h_t ready (published ~same wall-time as mine; bounded)
      poll_ge(flagPart, t + 1);
      if (!fast) __builtin_amdgcn_fence(__ATOMIC_ACQUIRE, "agent");
      asm volatile("" ::: "memory");
      // issue partner h_t loads (win t); latency hidden under own MFMAs
#pragma unroll
      for (int kk = 0; kk < 8; ++kk)
        pf[kk] = *(const short8*)(winCur + ((size_t)((half ^ 1) * 8 + kk)) * 512 + lane * 8);
      // own MFMAs for step t+1 (cover ds_read + pf latency)
#pragma unroll
      for (int kk = 0; kk < 8; ++kk)
#pragma unroll
        for (int p = 0; p < 2; ++p)
          accN[p] = __builtin_amdgcn_mfma_f32_16x16x32_bf16(wf[p * 16 + kk], hf[kk], accN[p], 0, 0, 0);
      acc[0] = accN[0];
      acc[1] = accN[1];
    }
  }
}

// ---------------------------------------------------------------------------
// Phase 3: out = hs @ W_hy + b_y.  hs is in frag layout:
// window (m0>>4) at (m0>>4)*8192 shorts, frag kt at kt*512 + lane*8.
// ---------------------------------------------------------------------------
__global__ __launch_bounds__(256) void out_gemm_kernel(
    const unsigned short* __restrict__ hs, const unsigned short* __restrict__ Why_p,
    const float* __restrict__ b_y, float* __restrict__ out) {
  const int tid = threadIdx.x;
  const int w = tid >> 6, lane = tid & 63;
  const int quad = lane >> 4, col16 = lane & 15;
  const int m0 = blockIdx.x * 64 + w * 16;

  f32x4 acc[8];
#pragma unroll
  for (int nt = 0; nt < 8; ++nt) acc[nt] = (f32x4){0.f,0.f,0.f,0.f};

  const unsigned short* aP = hs + (size_t)(m0 >> 4) * 8192 + lane * 8;
#pragma unroll
  for (int kt = 0; kt < 16; ++kt) {
    short8 a = *(const short8*)(aP + kt * 512);
#pragma unroll
    for (int nt = 0; nt < 8; ++nt) {
      int tile = nt * 16 + kt;                 // nKt(Why)=16
      short8 b = *(const short8*)(Why_p + (size_t)tile * 512 + lane * 8);
      acc[nt] = __builtin_amdgcn_mfma_f32_16x16x32_bf16(a, b, acc[nt], 0, 0, 0);
    }
  }
#pragma unroll
  for (int nt = 0; nt < 8; ++nt) {
    int n = nt * 16 + col16;
    float by = b_y[n];
#pragma unroll
    for (int r = 0; r < 4; ++r)
      out[(size_t)(m0 + quad * 4 + r) * 128 + n] = acc[nt][r] + by;
  }
}

// ---------------------------------------------------------------------------
extern "C" void kernel_launch(void* const* d_in, const int* in_sizes, int n_in,
                              void* d_out, int out_size, void* d_ws, size_t ws_size,
                              hipStream_t stream) {
  const float* x    = (const float*)d_in[0];   // [512,128,256]
  const float* W_xh = (const float*)d_in[1];   // [256,512]
  const float* W_hh = (const float*)d_in[2];   // [512,512]
  const float* W_hy = (const float*)d_in[3];   // [512,128]
  const float* b_h  = (const float*)d_in[4];   // [512]
  const float* b_y  = (const float*)d_in[5];   // [128]
  float* out = (float*)d_out;                  // [512,128,128]

  char* ws = (char*)d_ws;
  unsigned short* Wxh_p = (unsigned short*)(ws);                 // 256 KB
  unsigned short* Whh_p = (unsigned short*)(ws + (256 << 10));   // 512 KB
  unsigned short* Why_p = (unsigned short*)(ws + (768 << 10));   // 128 KB
  int*            flags = (int*)(ws + (960 << 10));              // 2 KB
  unsigned short* xhs   = (unsigned short*)(ws + (1024 << 10));  // 64 MB

  pack_b_kernel<<<64, 256, 0, stream>>>(W_xh, Wxh_p, 256, 512);
  pack_b_kernel<<<128, 256, 0, stream>>>(W_hh, Whh_p, 512, 512);
  pack_b_kernel<<<32, 256, 0, stream>>>(W_hy, Why_p, 512, 128);
  init_flags_kernel<<<1, 64, 0, stream>>>(flags);

  xh_gemm_kernel<<<1024, 256, 0, stream>>>(x, Wxh_p, b_h, xhs);

  rnn_recurrence_kernel<<<16, 512, 0, stream>>>(Whh_p, xhs, flags);

  out_gemm_kernel<<<1024, 256, 0, stream>>>(xhs, Why_p, b_y, out);
}